// Round 1
// baseline (2766.290 us; speedup 1.0000x reference)
//
#include <hip/hip_runtime.h>

#define IN_DIM 1433
#define HID 16
#define OUTD 7

#define KC 32
#define GROWS 256

// ---------------- GEMM1: xw1[N][16] = feat[N][1433] @ W1[1433][16] -------------
// Block = 256 threads, each thread owns one output row. K staged in LDS chunks
// of 32 (padded to 33 -> odd stride, conflict-free). W chunk (32x16) also in LDS,
// read as broadcast (free).
__global__ __launch_bounds__(256, 4) void gemm1_kernel(
    const float* __restrict__ feat, const float* __restrict__ W1,
    float* __restrict__ xw1, int N)
{
    __shared__ float xs[GROWS * (KC + 1)];   // 256*33*4 = 33792 B
    __shared__ float wsm[KC * HID];          // 2048 B
    const int t = threadIdx.x;
    const int row0 = blockIdx.x * GROWS;
    const int row = row0 + t;

    float acc[HID];
#pragma unroll
    for (int j = 0; j < HID; ++j) acc[j] = 0.f;

    const int kk_l = t & (KC - 1);   // 0..31
    const int r_l  = t >> 5;         // 0..7
    const int nIter = (IN_DIM + KC - 1) / KC;  // 45

    for (int it = 0; it < nIter; ++it) {
        const int k0 = it * KC;
        const int gk = k0 + kk_l;
        const bool kok = gk < IN_DIM;
        // stage x tile: 256x32 elements, 32 per thread, coalesced 128B segments
#pragma unroll
        for (int i = 0; i < GROWS / 8; ++i) {
            const int r = r_l + i * 8;
            const int grow = row0 + r;
            float v = 0.f;
            if (kok && grow < N) v = feat[(long)grow * IN_DIM + gk];
            xs[r * (KC + 1) + kk_l] = v;
        }
        // stage W chunk: 512 elements, 2 per thread
#pragma unroll
        for (int i = 0; i < (KC * HID) / 256; ++i) {
            const int e = t + i * 256;
            const int k = k0 + e / HID;
            wsm[e] = (k < IN_DIM) ? W1[(long)k * HID + (e % HID)] : 0.f;
        }
        __syncthreads();
#pragma unroll 8
        for (int kk = 0; kk < KC; ++kk) {
            const float x = xs[t * (KC + 1) + kk];
#pragma unroll
            for (int j = 0; j < HID; ++j)
                acc[j] += x * wsm[kk * HID + j];
        }
        __syncthreads();
    }

    if (row < N) {
        float4* o = (float4*)(xw1 + (long)row * HID);
        o[0] = make_float4(acc[0],  acc[1],  acc[2],  acc[3]);
        o[1] = make_float4(acc[4],  acc[5],  acc[6],  acc[7]);
        o[2] = make_float4(acc[8],  acc[9],  acc[10], acc[11]);
        o[3] = make_float4(acc[12], acc[13], acc[14], acc[15]);
    }
}

// ---------------- scatter layer 1: agg1[dst] += a * xw1[src], 16 dims ---------
// 4 threads per edge (one float4 chunk each) for parallelism.
__global__ __launch_bounds__(256) void scatter1_kernel(
    const int* __restrict__ src, const int* __restrict__ dst,
    const float* __restrict__ a, const float* __restrict__ xw1,
    float* __restrict__ agg1, int E)
{
    const long tid = (long)blockIdx.x * blockDim.x + threadIdx.x;
    const int e = (int)(tid >> 2);
    if (e >= E) return;
    const int c = (int)(tid & 3);
    const int s = src[e];
    const int d = dst[e];
    const float av = a[e];
    const float4 v = ((const float4*)(xw1 + (long)s * HID))[c];
    float* o = agg1 + (long)d * HID + c * 4;
    atomicAdd(o + 0, av * v.x);
    atomicAdd(o + 1, av * v.y);
    atomicAdd(o + 2, av * v.z);
    atomicAdd(o + 3, av * v.w);
}

// ---------------- h1 = relu(agg1 + b1); xw2 = h1 @ W2 (rows padded to 8) ------
__global__ __launch_bounds__(256) void transform2_kernel(
    const float* __restrict__ agg1, const float* __restrict__ b1,
    const float* __restrict__ W2, float* __restrict__ xw2, int N)
{
    __shared__ float w2s[HID * OUTD];
    __shared__ float b1s[HID];
    const int t = threadIdx.x;
    if (t < HID * OUTD) w2s[t] = W2[t];
    if (t < HID) b1s[t] = b1[t];
    __syncthreads();
    const int n = blockIdx.x * blockDim.x + t;
    if (n >= N) return;
    float h[HID];
    const float4* ap = (const float4*)(agg1 + (long)n * HID);
#pragma unroll
    for (int q = 0; q < 4; ++q) {
        float4 v = ap[q];
        h[q*4+0] = v.x; h[q*4+1] = v.y; h[q*4+2] = v.z; h[q*4+3] = v.w;
    }
#pragma unroll
    for (int j = 0; j < HID; ++j) {
        h[j] += b1s[j];
        h[j] = h[j] > 0.f ? h[j] : 0.f;
    }
    float o[8];
#pragma unroll
    for (int c = 0; c < OUTD; ++c) {
        float sacc = 0.f;
#pragma unroll
        for (int j = 0; j < HID; ++j) sacc += h[j] * w2s[j * OUTD + c];
        o[c] = sacc;
    }
    o[7] = 0.f;
    float4* op = (float4*)(xw2 + (long)n * 8);
    op[0] = make_float4(o[0], o[1], o[2], o[3]);
    op[1] = make_float4(o[4], o[5], o[6], o[7]);
}

// ---------------- scatter layer 2: agg2[dst] += a * xw2[src], 7 dims ----------
// 2 threads per edge: c=0 -> dims 0..3, c=1 -> dims 4..6.
__global__ __launch_bounds__(256) void scatter2_kernel(
    const int* __restrict__ src, const int* __restrict__ dst,
    const float* __restrict__ a, const float* __restrict__ xw2,
    float* __restrict__ agg2, int E)
{
    const long tid = (long)blockIdx.x * blockDim.x + threadIdx.x;
    const int e = (int)(tid >> 1);
    if (e >= E) return;
    const int c = (int)(tid & 1);
    const int s = src[e];
    const int d = dst[e];
    const float av = a[e];
    const float4 v = ((const float4*)(xw2 + (long)s * 8))[c];
    float* o = agg2 + (long)d * 8 + c * 4;
    atomicAdd(o + 0, av * v.x);
    atomicAdd(o + 1, av * v.y);
    atomicAdd(o + 2, av * v.z);
    if (c == 0) atomicAdd(o + 3, av * v.w);   // dim 7 is padding, skip for c==1
}

// ---------------- out = log_softmax(agg2[:, :7] + b2) -------------------------
__global__ __launch_bounds__(256) void lsm_kernel(
    const float* __restrict__ agg2, const float* __restrict__ b2,
    float* __restrict__ out, int N)
{
    __shared__ float b2s[OUTD];
    const int t = threadIdx.x;
    if (t < OUTD) b2s[t] = b2[t];
    __syncthreads();
    const int n = blockIdx.x * blockDim.x + t;
    if (n >= N) return;
    float x[OUTD];
    const float4* ap = (const float4*)(agg2 + (long)n * 8);
    float4 v0 = ap[0], v1 = ap[1];
    x[0]=v0.x; x[1]=v0.y; x[2]=v0.z; x[3]=v0.w; x[4]=v1.x; x[5]=v1.y; x[6]=v1.z;
#pragma unroll
    for (int c = 0; c < OUTD; ++c) x[c] += b2s[c];
    float m = x[0];
#pragma unroll
    for (int c = 1; c < OUTD; ++c) m = fmaxf(m, x[c]);
    float ssum = 0.f;
#pragma unroll
    for (int c = 0; c < OUTD; ++c) ssum += __expf(x[c] - m);
    const float l = __logf(ssum);
    float* op = out + (long)n * OUTD;
#pragma unroll
    for (int c = 0; c < OUTD; ++c) op[c] = x[c] - m - l;
}

extern "C" void kernel_launch(void* const* d_in, const int* in_sizes, int n_in,
                              void* d_out, int out_size, void* d_ws, size_t ws_size,
                              hipStream_t stream)
{
    const float* feat  = (const float*)d_in[0];
    const int*   esrc  = (const int*)d_in[1];
    const int*   edst  = (const int*)d_in[2];
    const float* avals = (const float*)d_in[3];
    const float* W1    = (const float*)d_in[4];
    const float* b1    = (const float*)d_in[5];
    const float* W2    = (const float*)d_in[6];
    const float* b2    = (const float*)d_in[7];
    float* out = (float*)d_out;

    const int N = in_sizes[0] / IN_DIM;   // 150000
    const int E = in_sizes[1];            // 4800000

    // workspace layout (floats): xw1[N*16] | xw2[N*8] | agg1[N*16] | agg2[N*8]
    float* xw1  = (float*)d_ws;
    float* xw2  = xw1 + (size_t)N * HID;
    float* agg1 = xw2 + (size_t)N * 8;
    float* agg2 = agg1 + (size_t)N * HID;

    // zero the two aggregation buffers (contiguous region of N*24 floats)
    hipMemsetAsync(agg1, 0, (size_t)N * 24 * sizeof(float), stream);

    gemm1_kernel<<<(N + GROWS - 1) / GROWS, 256, 0, stream>>>(feat, W1, xw1, N);

    {
        const long tot = (long)E * 4;
        scatter1_kernel<<<(int)((tot + 255) / 256), 256, 0, stream>>>(
            esrc, edst, avals, xw1, agg1, E);
    }

    transform2_kernel<<<(N + 255) / 256, 256, 0, stream>>>(agg1, b1, W2, xw2, N);

    {
        const long tot = (long)E * 2;
        scatter2_kernel<<<(int)((tot + 255) / 256), 256, 0, stream>>>(
            esrc, edst, avals, xw2, agg2, E);
    }

    lsm_kernel<<<(N + 255) / 256, 256, 0, stream>>>(agg2, b2, out, N);
}

// Round 2
// 1594.745 us; speedup vs baseline: 1.7346x; 1.7346x over previous
//
#include <hip/hip_runtime.h>
#include <float.h>
#include <stdint.h>

#define IN_DIM 1433
#define HID 16
#define OUTD 7

#define KC 32
#define GROWS 256

// ---------------- GEMM1: xw1[N][16] = feat[N][1433] @ W1[1433][16] -------------
__global__ __launch_bounds__(256, 4) void gemm1_kernel(
    const float* __restrict__ feat, const float* __restrict__ W1,
    float* __restrict__ xw1, int N)
{
    __shared__ float xs[GROWS * (KC + 1)];   // 256*33*4 = 33792 B
    __shared__ float wsm[KC * HID];          // 2048 B
    const int t = threadIdx.x;
    const int row0 = blockIdx.x * GROWS;
    const int row = row0 + t;

    float acc[HID];
#pragma unroll
    for (int j = 0; j < HID; ++j) acc[j] = 0.f;

    const int kk_l = t & (KC - 1);   // 0..31
    const int r_l  = t >> 5;         // 0..7
    const int nIter = (IN_DIM + KC - 1) / KC;  // 45

    for (int it = 0; it < nIter; ++it) {
        const int k0 = it * KC;
        const int gk = k0 + kk_l;
        const bool kok = gk < IN_DIM;
#pragma unroll
        for (int i = 0; i < GROWS / 8; ++i) {
            const int r = r_l + i * 8;
            const int grow = row0 + r;
            float v = 0.f;
            if (kok && grow < N) v = feat[(long)grow * IN_DIM + gk];
            xs[r * (KC + 1) + kk_l] = v;
        }
#pragma unroll
        for (int i = 0; i < (KC * HID) / 256; ++i) {
            const int e = t + i * 256;
            const int k = k0 + e / HID;
            wsm[e] = (k < IN_DIM) ? W1[(long)k * HID + (e % HID)] : 0.f;
        }
        __syncthreads();
#pragma unroll 8
        for (int kk = 0; kk < KC; ++kk) {
            const float x = xs[t * (KC + 1) + kk];
#pragma unroll
            for (int j = 0; j < HID; ++j)
                acc[j] += x * wsm[kk * HID + j];
        }
        __syncthreads();
    }

    if (row < N) {
        float4* o = (float4*)(xw1 + (long)row * HID);
        o[0] = make_float4(acc[0],  acc[1],  acc[2],  acc[3]);
        o[1] = make_float4(acc[4],  acc[5],  acc[6],  acc[7]);
        o[2] = make_float4(acc[8],  acc[9],  acc[10], acc[11]);
        o[3] = make_float4(acc[12], acc[13], acc[14], acc[15]);
    }
}

// ---------------- CSR build: histogram -> scan -> counting-sort fill ----------
__global__ __launch_bounds__(256) void hist_kernel(
    const int* __restrict__ dst, int* __restrict__ cnt, int E)
{
    const int e = blockIdx.x * 256 + threadIdx.x;
    if (e < E) atomicAdd(&cnt[dst[e]], 1);
}

// block = 256 threads, 4 elems/thread -> 1024 per block
__global__ __launch_bounds__(256) void scan1_kernel(
    const int* __restrict__ cnt, int* __restrict__ offs,
    int* __restrict__ bsum, int N)
{
    __shared__ int lds[256];
    const int t = threadIdx.x, b = blockIdx.x;
    const int base = b * 1024 + t * 4;
    int c0 = 0, c1 = 0, c2 = 0, c3 = 0;
    if (base + 0 < N) c0 = cnt[base + 0];
    if (base + 1 < N) c1 = cnt[base + 1];
    if (base + 2 < N) c2 = cnt[base + 2];
    if (base + 3 < N) c3 = cnt[base + 3];
    const int s = c0 + c1 + c2 + c3;
    lds[t] = s;
    __syncthreads();
    for (int off = 1; off < 256; off <<= 1) {
        int v = (t >= off) ? lds[t - off] : 0;
        __syncthreads();
        lds[t] += v;
        __syncthreads();
    }
    const int excl = lds[t] - s;
    if (t == 255) bsum[b] = lds[255];
    int run = excl;
    if (base + 0 < N) { offs[base + 0] = run; run += c0; }
    if (base + 1 < N) { offs[base + 1] = run; run += c1; }
    if (base + 2 < N) { offs[base + 2] = run; run += c2; }
    if (base + 3 < N) { offs[base + 3] = run; run += c3; }
}

// single block: exclusive scan of up to 256 block sums
__global__ __launch_bounds__(256) void scan2_kernel(
    const int* __restrict__ bsum, int* __restrict__ bbase, int NB)
{
    __shared__ int lds[256];
    const int t = threadIdx.x;
    const int v = (t < NB) ? bsum[t] : 0;
    lds[t] = v;
    __syncthreads();
    for (int off = 1; off < 256; off <<= 1) {
        int u = (t >= off) ? lds[t - off] : 0;
        __syncthreads();
        lds[t] += u;
        __syncthreads();
    }
    bbase[t] = lds[t] - v;
}

__global__ __launch_bounds__(256) void scan3_kernel(
    int* __restrict__ offs, int* __restrict__ cursor,
    const int* __restrict__ bbase, int N, int E)
{
    const int t = threadIdx.x, b = blockIdx.x;
    const int add = bbase[b];
    const int base = b * 1024 + t * 4;
#pragma unroll
    for (int i = 0; i < 4; ++i) {
        const int idx = base + i;
        if (idx < N) {
            const int v = offs[idx] + add;
            offs[idx] = v;
            cursor[idx] = v;
        }
    }
    if (b == 0 && t == 0) offs[N] = E;
}

__global__ __launch_bounds__(256) void fill_kernel(
    const int* __restrict__ src, const int* __restrict__ dst,
    const float* __restrict__ a, int* __restrict__ cursor,
    uint2* __restrict__ pairs, int E)
{
    const int e = blockIdx.x * 256 + threadIdx.x;
    if (e >= E) return;
    const int d = dst[e];
    const int pos = atomicAdd(&cursor[d], 1);
    pairs[pos] = make_uint2((unsigned)src[e], __float_as_uint(a[e]));
}

// ------- gather1: agg = sum(a*xw1[src]) ; fused h=relu(agg+b1); xw2 = h@W2 ----
// one wave per dst row: 16 lanes (dims) x 4 edge groups
__global__ __launch_bounds__(256) void gather1_kernel(
    const uint2* __restrict__ pairs, const int* __restrict__ offs,
    const float* __restrict__ xw1, const float* __restrict__ b1,
    const float* __restrict__ W2, float* __restrict__ xw2, int N)
{
    __shared__ float w2s[HID * OUTD];
    const int t = threadIdx.x;
    if (t < HID * OUTD) w2s[t] = W2[t];
    __syncthreads();
    const int lane = t & 63;
    const int r = blockIdx.x * 4 + (t >> 6);
    if (r >= N) return;
    const int dim = lane & 15;
    const int grp = lane >> 4;
    const int start = offs[r], end = offs[r + 1];
    float acc0 = 0.f, acc1 = 0.f;
    int e = start + grp;
    for (; e + 4 < end; e += 8) {
        const uint2 p0 = pairs[e];
        const uint2 p1 = pairs[e + 4];
        acc0 += __uint_as_float(p0.y) * xw1[(long)p0.x * HID + dim];
        acc1 += __uint_as_float(p1.y) * xw1[(long)p1.x * HID + dim];
    }
    if (e < end) {
        const uint2 p0 = pairs[e];
        acc0 += __uint_as_float(p0.y) * xw1[(long)p0.x * HID + dim];
    }
    float acc = acc0 + acc1;
    acc += __shfl_xor(acc, 16);
    acc += __shfl_xor(acc, 32);
    const float h = fmaxf(acc + b1[dim], 0.f);
    // xw2[c] = sum_j h_j * W2[j][c] via broadcast shuffles (lane j holds h_j)
    float sacc = 0.f;
    const int c = (dim < OUTD) ? dim : 0;
#pragma unroll
    for (int j = 0; j < HID; ++j) {
        const float hj = __shfl(h, j);
        sacc += hj * w2s[j * OUTD + c];
    }
    if (lane < 8) xw2[(long)r * 8 + lane] = (lane < OUTD) ? sacc : 0.f;
}

// ------- gather2: o = sum(a*xw2[src]) + b2 ; fused log_softmax -> out ---------
// one wave per dst row: 8 lanes (dims, dim7=pad) x 8 edge groups
__global__ __launch_bounds__(256) void gather2_kernel(
    const uint2* __restrict__ pairs, const int* __restrict__ offs,
    const float* __restrict__ xw2, const float* __restrict__ b2,
    float* __restrict__ out, int N)
{
    const int t = threadIdx.x;
    const int lane = t & 63;
    const int r = blockIdx.x * 4 + (t >> 6);
    if (r >= N) return;
    const int dim = lane & 7;
    const int grp = lane >> 3;
    const int start = offs[r], end = offs[r + 1];
    float acc0 = 0.f, acc1 = 0.f;
    int e = start + grp;
    for (; e + 8 < end; e += 16) {
        const uint2 p0 = pairs[e];
        const uint2 p1 = pairs[e + 8];
        acc0 += __uint_as_float(p0.y) * xw2[(long)p0.x * 8 + dim];
        acc1 += __uint_as_float(p1.y) * xw2[(long)p1.x * 8 + dim];
    }
    if (e < end) {
        const uint2 p0 = pairs[e];
        acc0 += __uint_as_float(p0.y) * xw2[(long)p0.x * 8 + dim];
    }
    float acc = acc0 + acc1;
    acc += __shfl_xor(acc, 8);
    acc += __shfl_xor(acc, 16);
    acc += __shfl_xor(acc, 32);
    float x = (dim < OUTD) ? (acc + b2[dim]) : -FLT_MAX;
    float m = x;
    m = fmaxf(m, __shfl_xor(m, 1));
    m = fmaxf(m, __shfl_xor(m, 2));
    m = fmaxf(m, __shfl_xor(m, 4));
    const float ev = (dim < OUTD) ? expf(x - m) : 0.f;
    float ssum = ev;
    ssum += __shfl_xor(ssum, 1);
    ssum += __shfl_xor(ssum, 2);
    ssum += __shfl_xor(ssum, 4);
    const float lg = logf(ssum);
    if (lane < OUTD) out[(long)r * OUTD + lane] = x - m - lg;
}

extern "C" void kernel_launch(void* const* d_in, const int* in_sizes, int n_in,
                              void* d_out, int out_size, void* d_ws, size_t ws_size,
                              hipStream_t stream)
{
    const float* feat  = (const float*)d_in[0];
    const int*   esrc  = (const int*)d_in[1];
    const int*   edst  = (const int*)d_in[2];
    const float* avals = (const float*)d_in[3];
    const float* W1    = (const float*)d_in[4];
    const float* b1    = (const float*)d_in[5];
    const float* W2    = (const float*)d_in[6];
    const float* b2    = (const float*)d_in[7];
    float* out = (float*)d_out;

    const int N = in_sizes[0] / IN_DIM;   // 150000
    const int E = in_sizes[1];            // 4800000
    const int NB = (N + 1023) / 1024;     // 147 (<=256 for scan2)

    // workspace layout
    char* p = (char*)d_ws;
    float* xw1   = (float*)p; p += (size_t)N * HID * sizeof(float);
    float* xw2   = (float*)p; p += (size_t)N * 8 * sizeof(float);
    int*   cnt   = (int*)p;   p += (size_t)N * sizeof(int);
    int*   offs  = (int*)p;   p += (size_t)(N + 1) * sizeof(int);
    int*   cursor= (int*)p;   p += (size_t)N * sizeof(int);
    int*   bsum  = (int*)p;   p += 256 * sizeof(int);
    int*   bbase = (int*)p;   p += 256 * sizeof(int);
    p = (char*)(((uintptr_t)p + 15) & ~(uintptr_t)15);
    uint2* pairs = (uint2*)p;

    hipMemsetAsync(cnt, 0, (size_t)N * sizeof(int), stream);

    gemm1_kernel<<<(N + GROWS - 1) / GROWS, 256, 0, stream>>>(feat, W1, xw1, N);

    hist_kernel<<<(E + 255) / 256, 256, 0, stream>>>(edst, cnt, E);
    scan1_kernel<<<NB, 256, 0, stream>>>(cnt, offs, bsum, N);
    scan2_kernel<<<1, 256, 0, stream>>>(bsum, bbase, NB);
    scan3_kernel<<<NB, 256, 0, stream>>>(offs, cursor, bbase, N, E);
    fill_kernel<<<(E + 255) / 256, 256, 0, stream>>>(esrc, edst, avals, cursor, pairs, E);

    gather1_kernel<<<(N + 3) / 4, 256, 0, stream>>>(pairs, offs, xw1, b1, W2, xw2, N);
    gather2_kernel<<<(N + 3) / 4, 256, 0, stream>>>(pairs, offs, xw2, b2, out, N);
}

// Round 3
// 1054.541 us; speedup vs baseline: 2.6232x; 1.5123x over previous
//
#include <hip/hip_runtime.h>
#include <float.h>
#include <stdint.h>

#define IN_DIM 1433
#define HID 16
#define OUTD 7

#define KC 32
#define GROWS 128
#define NT ((IN_DIM + KC - 1) / KC)      // 45 tiles
#define KLAST (IN_DIM - (NT - 1) * KC)   // 25

// ---------------- GEMM1: xw1[N][16] = feat[N][1433] @ W1[1433][16] -------------
// 256 threads = 4 waves. 128 rows/block, 2 threads per row (8 dims each).
// Double-buffered LDS tile xs[2][128][32], staged via async global_load_lds
// (linear LDS dest; bank-conflict fixed by pre-swizzling the GLOBAL source
// address with col ^ (row&31), same XOR applied on the read side).
// W1 read through a wave-uniform (readfirstlane) pointer -> scalar loads.
__global__ __launch_bounds__(256, 4) void gemm1_kernel(
    const float* __restrict__ feat, const float* __restrict__ W1,
    float* __restrict__ xw1, int N)
{
    __shared__ float xs[2][GROWS * KC];   // 2 * 16 KB
    const int t = threadIdx.x;
    const int lane = t & 63;
    const int wid = t >> 6;
    const int row0 = blockIdx.x * GROWS;
    const long maxElem = (long)N * IN_DIM - 1;

    const int r  = t & (GROWS - 1);   // row within tile
    const int jh = t >> 7;            // 0: dims 0-7, 1: dims 8-15
    const int rx = r & 31;            // read-side swizzle key

    float acc[8];
#pragma unroll
    for (int j = 0; j < 8; ++j) acc[j] = 0.f;

    const int jhu = __builtin_amdgcn_readfirstlane(jh);
    const float* __restrict__ wptr = W1 + jhu * 8;

    const int l5 = lane >> 5;   // 0/1: which of the 2 rows per instruction
    const int c  = lane & 31;   // column slot within the row

    // stage one 128x32 tile (async). Per wave: 16 insts x 2 rows x 32 floats.
    auto stage = [&](int buf, int k0) {
#pragma unroll
        for (int i = 0; i < 16; ++i) {
            const int rr = wid * 32 + i * 2 + l5;
            long elem = (long)(row0 + rr) * IN_DIM + k0 + (c ^ (rr & 31));
            if (elem > maxElem) elem = maxElem;   // row/k tail clamp
            const float* gp = feat + elem;
            float* lp = &xs[buf][(wid * 32 + i * 2) * KC];  // wave-uniform base
            __builtin_amdgcn_global_load_lds(
                (const __attribute__((address_space(1))) void*)gp,
                (__attribute__((address_space(3))) void*)lp, 4, 0, 0);
        }
    };

#define COMPUTE(buf, k0v, KMAX)                                          \
    {                                                                    \
        const float* xrow = &xs[buf][r * KC];                            \
        const float* wk = wptr + (size_t)(k0v) * HID;                    \
        _Pragma("unroll")                                                \
        for (int kk = 0; kk < (KMAX); ++kk) {                            \
            const float x = xrow[kk ^ rx];                               \
            const float4 wa = *(const float4*)(wk + kk * HID);           \
            const float4 wb = *(const float4*)(wk + kk * HID + 4);       \
            acc[0] += x * wa.x; acc[1] += x * wa.y;                      \
            acc[2] += x * wa.z; acc[3] += x * wa.w;                      \
            acc[4] += x * wb.x; acc[5] += x * wb.y;                      \
            acc[6] += x * wb.z; acc[7] += x * wb.w;                      \
        }                                                                \
    }

    stage(0, 0);
    __syncthreads();   // drains vmcnt -> tile 0 resident
    for (int it = 0; it < NT - 1; ++it) {
        const int cur = it & 1;
        stage(cur ^ 1, (it + 1) * KC);    // async prefetch next tile
        COMPUTE(cur, it * KC, KC);        // compute current tile
        __syncthreads();                  // drain prefetch + protect reuse
    }
    COMPUTE((NT - 1) & 1, (NT - 1) * KC, KLAST);
#undef COMPUTE

    const int grow = row0 + r;
    if (grow < N) {
        float4* o = (float4*)(xw1 + (size_t)grow * HID + jh * 8);
        o[0] = make_float4(acc[0], acc[1], acc[2], acc[3]);
        o[1] = make_float4(acc[4], acc[5], acc[6], acc[7]);
    }
}

// ---------------- CSR build: histogram -> scan -> counting-sort fill ----------
__global__ __launch_bounds__(256) void hist_kernel(
    const int* __restrict__ dst, int* __restrict__ cnt, int E)
{
    const int e = blockIdx.x * 256 + threadIdx.x;
    if (e < E) atomicAdd(&cnt[dst[e]], 1);
}

// block = 256 threads, 4 elems/thread -> 1024 per block
__global__ __launch_bounds__(256) void scan1_kernel(
    const int* __restrict__ cnt, int* __restrict__ offs,
    int* __restrict__ bsum, int N)
{
    __shared__ int lds[256];
    const int t = threadIdx.x, b = blockIdx.x;
    const int base = b * 1024 + t * 4;
    int c0 = 0, c1 = 0, c2 = 0, c3 = 0;
    if (base + 0 < N) c0 = cnt[base + 0];
    if (base + 1 < N) c1 = cnt[base + 1];
    if (base + 2 < N) c2 = cnt[base + 2];
    if (base + 3 < N) c3 = cnt[base + 3];
    const int s = c0 + c1 + c2 + c3;
    lds[t] = s;
    __syncthreads();
    for (int off = 1; off < 256; off <<= 1) {
        int v = (t >= off) ? lds[t - off] : 0;
        __syncthreads();
        lds[t] += v;
        __syncthreads();
    }
    const int excl = lds[t] - s;
    if (t == 255) bsum[b] = lds[255];
    int run = excl;
    if (base + 0 < N) { offs[base + 0] = run; run += c0; }
    if (base + 1 < N) { offs[base + 1] = run; run += c1; }
    if (base + 2 < N) { offs[base + 2] = run; run += c2; }
    if (base + 3 < N) { offs[base + 3] = run; run += c3; }
}

// single block: exclusive scan of up to 256 block sums
__global__ __launch_bounds__(256) void scan2_kernel(
    const int* __restrict__ bsum, int* __restrict__ bbase, int NB)
{
    __shared__ int lds[256];
    const int t = threadIdx.x;
    const int v = (t < NB) ? bsum[t] : 0;
    lds[t] = v;
    __syncthreads();
    for (int off = 1; off < 256; off <<= 1) {
        int u = (t >= off) ? lds[t - off] : 0;
        __syncthreads();
        lds[t] += u;
        __syncthreads();
    }
    bbase[t] = lds[t] - v;
}

__global__ __launch_bounds__(256) void scan3_kernel(
    int* __restrict__ offs, int* __restrict__ cursor,
    const int* __restrict__ bbase, int N, int E)
{
    const int t = threadIdx.x, b = blockIdx.x;
    const int add = bbase[b];
    const int base = b * 1024 + t * 4;
#pragma unroll
    for (int i = 0; i < 4; ++i) {
        const int idx = base + i;
        if (idx < N) {
            const int v = offs[idx] + add;
            offs[idx] = v;
            cursor[idx] = v;
        }
    }
    if (b == 0 && t == 0) offs[N] = E;
}

__global__ __launch_bounds__(256) void fill_kernel(
    const int* __restrict__ src, const int* __restrict__ dst,
    const float* __restrict__ a, int* __restrict__ cursor,
    uint2* __restrict__ pairs, int E)
{
    const int e = blockIdx.x * 256 + threadIdx.x;
    if (e >= E) return;
    const int d = dst[e];
    const int pos = atomicAdd(&cursor[d], 1);
    pairs[pos] = make_uint2((unsigned)src[e], __float_as_uint(a[e]));
}

// ------- gather1: agg = sum(a*xw1[src]) ; fused h=relu(agg+b1); xw2 = h@W2 ----
// one wave per dst row: 16 lanes (dims) x 4 edge groups
__global__ __launch_bounds__(256) void gather1_kernel(
    const uint2* __restrict__ pairs, const int* __restrict__ offs,
    const float* __restrict__ xw1, const float* __restrict__ b1,
    const float* __restrict__ W2, float* __restrict__ xw2, int N)
{
    __shared__ float w2s[HID * OUTD];
    const int t = threadIdx.x;
    if (t < HID * OUTD) w2s[t] = W2[t];
    __syncthreads();
    const int lane = t & 63;
    const int r = blockIdx.x * 4 + (t >> 6);
    if (r >= N) return;
    const int dim = lane & 15;
    const int grp = lane >> 4;
    const int start = offs[r], end = offs[r + 1];
    float acc0 = 0.f, acc1 = 0.f;
    int e = start + grp;
    for (; e + 4 < end; e += 8) {
        const uint2 p0 = pairs[e];
        const uint2 p1 = pairs[e + 4];
        acc0 += __uint_as_float(p0.y) * xw1[(long)p0.x * HID + dim];
        acc1 += __uint_as_float(p1.y) * xw1[(long)p1.x * HID + dim];
    }
    if (e < end) {
        const uint2 p0 = pairs[e];
        acc0 += __uint_as_float(p0.y) * xw1[(long)p0.x * HID + dim];
    }
    float acc = acc0 + acc1;
    acc += __shfl_xor(acc, 16);
    acc += __shfl_xor(acc, 32);
    const float h = fmaxf(acc + b1[dim], 0.f);
    float sacc = 0.f;
    const int c = (dim < OUTD) ? dim : 0;
#pragma unroll
    for (int j = 0; j < HID; ++j) {
        const float hj = __shfl(h, j);
        sacc += hj * w2s[j * OUTD + c];
    }
    if (lane < 8) xw2[(long)r * 8 + lane] = (lane < OUTD) ? sacc : 0.f;
}

// ------- gather2: o = sum(a*xw2[src]) + b2 ; fused log_softmax -> out ---------
__global__ __launch_bounds__(256) void gather2_kernel(
    const uint2* __restrict__ pairs, const int* __restrict__ offs,
    const float* __restrict__ xw2, const float* __restrict__ b2,
    float* __restrict__ out, int N)
{
    const int t = threadIdx.x;
    const int lane = t & 63;
    const int r = blockIdx.x * 4 + (t >> 6);
    if (r >= N) return;
    const int dim = lane & 7;
    const int grp = lane >> 3;
    const int start = offs[r], end = offs[r + 1];
    float acc0 = 0.f, acc1 = 0.f;
    int e = start + grp;
    for (; e + 8 < end; e += 16) {
        const uint2 p0 = pairs[e];
        const uint2 p1 = pairs[e + 8];
        acc0 += __uint_as_float(p0.y) * xw2[(long)p0.x * 8 + dim];
        acc1 += __uint_as_float(p1.y) * xw2[(long)p1.x * 8 + dim];
    }
    if (e < end) {
        const uint2 p0 = pairs[e];
        acc0 += __uint_as_float(p0.y) * xw2[(long)p0.x * 8 + dim];
    }
    float acc = acc0 + acc1;
    acc += __shfl_xor(acc, 8);
    acc += __shfl_xor(acc, 16);
    acc += __shfl_xor(acc, 32);
    float x = (dim < OUTD) ? (acc + b2[dim]) : -FLT_MAX;
    float m = x;
    m = fmaxf(m, __shfl_xor(m, 1));
    m = fmaxf(m, __shfl_xor(m, 2));
    m = fmaxf(m, __shfl_xor(m, 4));
    const float ev = (dim < OUTD) ? expf(x - m) : 0.f;
    float ssum = ev;
    ssum += __shfl_xor(ssum, 1);
    ssum += __shfl_xor(ssum, 2);
    ssum += __shfl_xor(ssum, 4);
    const float lg = logf(ssum);
    if (lane < OUTD) out[(long)r * OUTD + lane] = x - m - lg;
}

extern "C" void kernel_launch(void* const* d_in, const int* in_sizes, int n_in,
                              void* d_out, int out_size, void* d_ws, size_t ws_size,
                              hipStream_t stream)
{
    const float* feat  = (const float*)d_in[0];
    const int*   esrc  = (const int*)d_in[1];
    const int*   edst  = (const int*)d_in[2];
    const float* avals = (const float*)d_in[3];
    const float* W1    = (const float*)d_in[4];
    const float* b1    = (const float*)d_in[5];
    const float* W2    = (const float*)d_in[6];
    const float* b2    = (const float*)d_in[7];
    float* out = (float*)d_out;

    const int N = in_sizes[0] / IN_DIM;   // 150000
    const int E = in_sizes[1];            // 4800000
    const int NB = (N + 1023) / 1024;     // 147 (<=256 for scan2)

    // workspace layout
    char* p = (char*)d_ws;
    float* xw1   = (float*)p; p += (size_t)N * HID * sizeof(float);
    float* xw2   = (float*)p; p += (size_t)N * 8 * sizeof(float);
    int*   cnt   = (int*)p;   p += (size_t)N * sizeof(int);
    int*   offs  = (int*)p;   p += (size_t)(N + 1) * sizeof(int);
    int*   cursor= (int*)p;   p += (size_t)N * sizeof(int);
    int*   bsum  = (int*)p;   p += 256 * sizeof(int);
    int*   bbase = (int*)p;   p += 256 * sizeof(int);
    p = (char*)(((uintptr_t)p + 15) & ~(uintptr_t)15);
    uint2* pairs = (uint2*)p;

    hipMemsetAsync(cnt, 0, (size_t)N * sizeof(int), stream);

    gemm1_kernel<<<(N + GROWS - 1) / GROWS, 256, 0, stream>>>(feat, W1, xw1, N);

    hist_kernel<<<(E + 255) / 256, 256, 0, stream>>>(edst, cnt, E);
    scan1_kernel<<<NB, 256, 0, stream>>>(cnt, offs, bsum, N);
    scan2_kernel<<<1, 256, 0, stream>>>(bsum, bbase, NB);
    scan3_kernel<<<NB, 256, 0, stream>>>(offs, cursor, bbase, N, E);
    fill_kernel<<<(E + 255) / 256, 256, 0, stream>>>(esrc, edst, avals, cursor, pairs, E);

    gather1_kernel<<<(N + 3) / 4, 256, 0, stream>>>(pairs, offs, xw1, b1, W2, xw2, N);
    gather2_kernel<<<(N + 3) / 4, 256, 0, stream>>>(pairs, offs, xw2, b2, out, N);
}